// Round 8
// baseline (16712.752 us; speedup 1.0000x reference)
//
#include <hip/hip_runtime.h>
#include <cstdint>
#include <cstddef>

#define TT 512
#define BB 64
#define II 256
#define HH 512
#define OO 64
#define NWG 256   // scan workgroups: one per CU (forced by LDS footprint)
#define TAGPAD 16 // dwords between tags (64B -> distinct LLC lines)

// DPP quad-perm cross-lane adds (VALU, not LDS pipe):
// xor1: perm [1,0,3,2] = 0xB1 ; xor2: perm [2,3,0,1] = 0x4E
__device__ __forceinline__ float xor1_dpp(float v) {
    return __int_as_float(__builtin_amdgcn_update_dpp(
        0, __float_as_int(v), 0xB1, 0xF, 0xF, true));
}
__device__ __forceinline__ float xor2_dpp(float v) {
    return __int_as_float(__builtin_amdgcn_update_dpp(
        0, __float_as_int(v), 0x4E, 0xF, 0xF, true));
}

// ---------------- Fused x-proj + XCD-local persistent GRU scan -----------
// r7 skeleton (3 barriers, tid<32 LLC poll sc0sc1, plain h stores, B3 drain,
// tid0 release) with:
//  * SINGLE combined 8-slot reduce {r,u,x_n,h_n}x2cols: x- and h-partials
//    for r/u gates summed in-register pre-reduce (algebraically identical:
//    sigmoid(Sx+Sh+bx+bh)); n-gate keeps separate x/h sums (reset scales
//    only the h part). Replaces r7's two 6-slot reduces (24->12 shfl).
//  * x2h weights in VGPRs (wxreg[6][4], 24 regs) - no wx LDS reads.
//  * h(t-1) global load issued at B1, x-matvec runs while it flies,
//    ds_write after -> L2 latency hidden.
// Tags stay LLC-scope sc0 sc1 (round-3 lesson). Lane-permuted rows
// (r0=2s1+s0, r1=r0^2, r2=r0^1, r3=r0^3; weight col ^s2) -> cndmask-free.
__global__ __launch_bounds__(1024, 4)
void scan_kernel(const float* __restrict__ x,  const float* __restrict__ xw,
                 const float* __restrict__ xb, const float* __restrict__ hw,
                 const float* __restrict__ hbias, float* __restrict__ rnn,
                 int* __restrict__ tags)
{
    __shared__ float hlds[8 * 512];     // 16KB: h(t-1)
    __shared__ float xlds[8 * 256];     // 8KB:  x(t)
    __shared__ float pad_[14848];       // 58KB ballast -> ~82KB -> 1 WG/CU
    __shared__ int s_rk;

    const int tid = threadIdx.x;
    ((volatile float*)pad_)[tid] = 0.f;  // keep ballast allocated

    int xcc;
    asm volatile("s_getreg_b32 %0, hwreg(HW_REG_XCC_ID)" : "=s"(xcc));
    const int g = xcc & 7;               // group = physical XCD
    if (tid == 0) {
        __threadfence();                 // one-time: drop stale/poison lines
        s_rk = atomicAdd(tags + NWG * TAGPAD + g * 16, 1); // rank in XCD
    }
    __syncthreads();
    const int rk = s_rk;
    if (rk >= 32) return;                // cannot happen with 1 WG/CU

    const int w    = tid >> 6;           // wave 0..15
    const int l    = tid & 63;           // lane
    const int cp   = w >> 1;             // column pair 0..7
    const int bh   = w & 1;              // batch half 0..1
    const int c0w  = rk * 16 + 2 * cp;   // wave's first column
    const int s0 = l & 1, s1 = (l >> 1) & 1, s2 = (l >> 2) & 1;
    const int col  = c0w + s2;                 // epilogue column (lanes l<8)
    const int ob   = 8 * g + 4 * bh + (l & 3); // epilogue batch row (global)

    // h staging map: thread stages 4 contiguous floats
    const int sb    = tid >> 7;
    const int sk    = (tid & 127) * 4;
    const int soff  = sb * 512 + sk;
    const int hsoff = (8 * g + sb) * HH + sk;
    // x staging map: thread stages 2 contiguous floats
    const int sk2   = (tid & 127) * 2;
    const int soff2 = sb * 256 + sk2;
    const int xgoff = (8 * g + sb) * II + sk2;

    // poll: lanes tid<32 poll rank-tid's tag (LLC); tid0 releases ours
    const int* tpoll = tags + ((size_t)g * 32 + (tid & 31)) * TAGPAD;
    int* tagme       = (int*)(tags + ((size_t)g * 32 + rk) * TAGPAD);

    // lane-permuted rows for cndmask-free transpose-reduce
    const int r0 = 2*s1 + s0, r1 = r0 ^ 2, r2 = r0 ^ 1, r3 = r0 ^ 3;
    const int roff0 = (4*bh + r0) * 512 + 4*l;
    const int roff1 = (4*bh + r1) * 512 + 4*l;
    const int roff2 = (4*bh + r2) * 512 + 4*l;
    const int roff3 = (4*bh + r3) * 512 + 4*l;
    const int xoff0 = (4*bh + r0) * 256 + 4*l;
    const int xoff1 = (4*bh + r1) * 256 + 4*l;
    const int xoff2 = (4*bh + r2) * 256 + 4*l;
    const int xoff3 = (4*bh + r3) * 256 + 4*l;

    // x2h weights -> registers: slot s=2*gate+par, col = c0w + (par^s2)
    float wxreg[6][4];
#pragma unroll
    for (int s = 0; s < 6; ++s) {
        const float* wp = xw + ((size_t)(s >> 1) * HH + c0w + ((s & 1) ^ s2)) * II + 4 * l;
        float4 v = *(const float4*)wp;
        wxreg[s][0] = v.x; wxreg[s][1] = v.y; wxreg[s][2] = v.z; wxreg[s][3] = v.w;
    }
    // h2h weights -> registers: rr=2*gate+par (slots: rr<4 -> rr, else rr+2)
    float wreg[6][8];
#pragma unroll
    for (int rr = 0; rr < 6; ++rr) {
        const float* wp = hw + ((size_t)(rr >> 1) * HH + c0w + ((rr & 1) ^ s2)) * HH;
        float4 a = *(const float4*)(wp + 4 * l);
        float4 b = *(const float4*)(wp + 256 + 4 * l);
        wreg[rr][0] = a.x; wreg[rr][1] = a.y; wreg[rr][2] = a.z; wreg[rr][3] = a.w;
        wreg[rr][4] = b.x; wreg[rr][5] = b.y; wreg[rr][6] = b.z; wreg[rr][7] = b.w;
    }
    // combined biases (r/u) + separate n-gate biases
    const float br_  = xb[col] + hbias[col];
    const float bu_  = xb[HH + col] + hbias[HH + col];
    const float bxn_ = xb[2 * HH + col];
    const float bhn_ = hbias[2 * HH + col];

    // stage x[0]
    *(float2*)(xlds + soff2) = *(const float2*)(x + xgoff);
    __syncthreads();   // xlds ready

    float hloc = 0.f;            // lanes l<8: my (b,c) previous h (exact fp32)
    long long budget = 4000000;  // spin bound: bug -> wrong answer, not hang

    // x-matvec row: slots 0..5 = x-partials; 6,7 (h_n) zeroed
#define XROW(R, XOFF) { \
        float4 xv = *(const float4*)(xlds + (XOFF)); \
        _Pragma("unroll") \
        for (int s = 0; s < 6; ++s) \
            acc[R][s] = fmaf(xv.w, wxreg[s][3], fmaf(xv.z, wxreg[s][2], \
                        fmaf(xv.y, wxreg[s][1], xv.x * wxreg[s][0]))); \
        acc[R][6] = 0.f; acc[R][7] = 0.f; }

    // h-matvec row: r/u add into slots 0..3; n into slots 6,7
#define HROW(R, ROFF) { \
        float4 hA = *(const float4*)(hlds + (ROFF)); \
        float4 hB = *(const float4*)(hlds + (ROFF) + 256); \
        _Pragma("unroll") \
        for (int rr = 0; rr < 6; ++rr) { \
            const int s = (rr < 4) ? rr : (rr + 2); \
            float a = acc[R][s]; \
            a = fmaf(hA.x, wreg[rr][0], a); a = fmaf(hA.y, wreg[rr][1], a); \
            a = fmaf(hA.z, wreg[rr][2], a); a = fmaf(hA.w, wreg[rr][3], a); \
            a = fmaf(hB.x, wreg[rr][4], a); a = fmaf(hB.y, wreg[rr][5], a); \
            a = fmaf(hB.z, wreg[rr][6], a); a = fmaf(hB.w, wreg[rr][7], a); \
            acc[R][s] = a; } }

    for (int t = 0; t < TT; ++t) {
        // prefetch x(t+1) (completes under poll's vmcnt or x-matvec)
        const int tn = (t + 1 < TT) ? t + 1 : TT - 1;
        const float2 xnv = *(const float2*)(x + ((size_t)tn << 14) + xgoff);

        float acc[4][8];
        if (t > 0) {
            if (tid < 32) {  // poll the 32 group tags (LLC)
                int v;
                do {
                    asm volatile("global_load_dword %0, %1, off sc0 sc1\n\t"
                                 "s_waitcnt vmcnt(0)"
                                 : "=v"(v) : "v"(tpoll) : "memory");
                    if (v >= t) break;
                    __builtin_amdgcn_s_sleep(1);
                } while (--budget > 0);
            }
            __syncthreads(); // B1: h(t-1) complete in this XCD's L2

            // issue h(t-1) load; x-matvec hides its L2 latency
            const float4 hv = *(const float4*)(rnn + ((size_t)(t - 1) << 15) + hsoff);
            XROW(0, xoff0) XROW(1, xoff1) XROW(2, xoff2) XROW(3, xoff3)
            *(float4*)(hlds + soff) = hv;   // compiler waits vmcnt here
            __syncthreads(); // B2: h staged

            *(float2*)(xlds + soff2) = xnv; // restage x(t+1); reads were pre-B2

            HROW(0, roff0) HROW(1, roff1) HROW(2, roff2) HROW(3, roff3)
        } else {
            XROW(0, xoff0) XROW(1, xoff1) XROW(2, xoff2) XROW(3, xoff3)
            __syncthreads();                // xlds reads done
            *(float2*)(xlds + soff2) = xnv; // restage x(1)
        }

        // single 8-slot cndmask-free transpose-reduce
        float t0[8], t1[8], a2v[8], a3[4];
#pragma unroll
        for (int s = 0; s < 8; ++s) {
            t0[s] = acc[0][s] + xor1_dpp(acc[2][s]);
            t1[s] = acc[1][s] + xor1_dpp(acc[3][s]);
        }
#pragma unroll
        for (int s = 0; s < 8; ++s)
            a2v[s] = t0[s] + xor2_dpp(t1[s]);
#pragma unroll
        for (int gi = 0; gi < 4; ++gi)
            a3[gi] = a2v[2*gi] + __shfl_xor(a2v[2*gi + 1], 4, 64);
#pragma unroll
        for (int gi = 0; gi < 4; ++gi) {
            a3[gi] += __shfl_xor(a3[gi], 8, 64);
            a3[gi] += __shfl_xor(a3[gi], 16, 64);
            a3[gi] += __shfl_xor(a3[gi], 32, 64);
        }

        if (l < 8) { // one lane per output (b=ob, c=col)
            float rg = 1.f / (1.f + __expf(-(a3[0] + br_)));
            float ug = 1.f / (1.f + __expf(-(a3[1] + bu_)));
            // h2h bias of n-gate sits INSIDE reset*(...), per reference
            float npre = (a3[2] + bxn_) + rg * (a3[3] + bhn_);
            float e  = __expf(-2.f * npre);
            float nv = 2.f / (1.f + e) - 1.f;
            float hy = ug * hloc + (1.f - ug) * nv;
            hloc = hy;
            float* dstp = rnn + ((size_t)t << 15) + ob * HH + col;
            // plain store: write-through into this XCD's L2
            asm volatile("global_store_dword %0, %1, off"
                         :: "v"(dstp), "v"(hy) : "memory");
        }
        asm volatile("s_waitcnt vmcnt(0)" ::: "memory"); // h stores drained
        __syncthreads(); // B3: all waves' stores + xlds restage complete
        if (tid == 0) {
            int tv = t + 1;
            asm volatile("global_store_dword %0, %1, off sc0 sc1"
                         :: "v"(tagme), "v"(tv) : "memory");
        }
    }
#undef XROW
#undef HROW
}

// ---------------- Phase C: fc output (unchanged) ----------------
__global__ __launch_bounds__(256)
void fc_kernel(const float* __restrict__ rnn, const float* __restrict__ fcw,
               const float* __restrict__ fcb, float* __restrict__ out)
{
    __shared__ float wlds[128][65];
    const int t = blockIdx.x;
    const int tid = threadIdx.x;
    const int o  = tid & 63;
    const int bg = tid >> 6;
    float acc[16];
#pragma unroll
    for (int i = 0; i < 16; ++i) acc[i] = 0.f;

    for (int kc = 0; kc < 4; ++kc) {
        const int k0 = kc * 128;
        __syncthreads();
        for (int idx = tid; idx < 64 * 32; idx += 256) {
            int oo = idx >> 5, kq = (idx & 31) * 4;
            float4 v = *(const float4*)(fcw + (size_t)oo * HH + k0 + kq);
            wlds[kq][oo] = v.x; wlds[kq+1][oo] = v.y;
            wlds[kq+2][oo] = v.z; wlds[kq+3][oo] = v.w;
        }
        __syncthreads();
#pragma unroll 2
        for (int k4 = 0; k4 < 32; ++k4) {
            float w0 = wlds[k4*4+0][o], w1 = wlds[k4*4+1][o];
            float w2 = wlds[k4*4+2][o], w3 = wlds[k4*4+3][o];
#pragma unroll
            for (int i = 0; i < 16; ++i) {
                int bb = bg * 16 + i;
                float4 h4 = *(const float4*)(rnn + ((size_t)t * BB + bb) * HH + k0 + k4*4);
                acc[i] = fmaf(h4.x, w0, fmaf(h4.y, w1, fmaf(h4.z, w2, fmaf(h4.w, w3, acc[i]))));
            }
        }
    }
    float bo = fcb[o];
#pragma unroll
    for (int i = 0; i < 16; ++i) {
        int bb = bg * 16 + i;
        out[((size_t)t * BB + bb) * OO + o] = acc[i] + bo;
    }
}

extern "C" void kernel_launch(void* const* d_in, const int* in_sizes, int n_in,
                              void* d_out, int out_size, void* d_ws, size_t ws_size,
                              hipStream_t stream)
{
    const float* x     = (const float*)d_in[0];
    const float* x2h_w = (const float*)d_in[1];
    const float* x2h_b = (const float*)d_in[2];
    const float* h2h_w = (const float*)d_in[3];
    const float* h2h_b = (const float*)d_in[4];
    const float* fc_w  = (const float*)d_in[5];
    const float* fc_b  = (const float*)d_in[6];

    float* out = (float*)d_out;                        // [T][B][O]
    float* rnn = (float*)d_out + (size_t)TT * BB * OO; // [T][B][H]

    int* tags = (int*)d_ws;                            // 256 WG tags + rank ctrs

    hipMemsetAsync(tags, 0, (NWG * TAGPAD + 8 * 16) * sizeof(int), stream);

    scan_kernel<<<NWG, 1024, 0, stream>>>(x, x2h_w, x2h_b, h2h_w, h2h_b, rnn, tags);
    fc_kernel<<<TT, 256, 0, stream>>>(rnn, fc_w, fc_b, out);
}

// Round 9
// 8276.082 us; speedup vs baseline: 2.0194x; 2.0194x over previous
//
#include <hip/hip_runtime.h>
#include <cstdint>
#include <cstddef>

#define TT 512
#define BB 64
#define II 256
#define HH 512
#define OO 64
#define NWG 256   // scan workgroups: one per CU (forced by LDS footprint)
#define TAGPAD 16 // dwords between tags (64B -> distinct LLC lines)

// DPP quad-perm cross-lane adds (VALU, not LDS pipe):
// xor1: perm [1,0,3,2] = 0xB1 ; xor2: perm [2,3,0,1] = 0x4E
__device__ __forceinline__ float xor1_dpp(float v) {
    return __int_as_float(__builtin_amdgcn_update_dpp(
        0, __float_as_int(v), 0xB1, 0xF, 0xF, true));
}
__device__ __forceinline__ float xor2_dpp(float v) {
    return __int_as_float(__builtin_amdgcn_update_dpp(
        0, __float_as_int(v), 0x4E, 0xF, 0xF, true));
}

// ---------------- Fused x-proj + XCD-local persistent GRU scan -----------
// r7 skeleton + codegen (3 barriers, tid<32 LLC poll sc0sc1, wx in LDS,
// 1-D acc arrays with constant-bound unrolled loops -- NO macros, NO 2-D
// arrays, NO conditional indices: r8's scratch-demotion lesson) with r8's
// verified algorithm:
//  * SINGLE combined 8-slot reduce {r,u,x_n,h_n}x2cols: x/h partials for
//    r,u summed in-register pre-reduce; n-gate keeps x,h separate (reset
//    scales only the h part). Slots: 0,1=r; 2,3=u; 4,5=x_n; 6,7=h_n.
//  * h(t-1) global load issued before the x-matvec (L2 latency hidden).
// Tags LLC-scope sc0 sc1 (round-3 lesson). Lane-permuted rows
// (r0=2s1+s0, r1=r0^2, r2=r0^1, r3=r0^3; weight col ^s2) -> cndmask-free.
__global__ __launch_bounds__(1024, 4)
void scan_kernel(const float* __restrict__ x,  const float* __restrict__ xw,
                 const float* __restrict__ xb, const float* __restrict__ hw,
                 const float* __restrict__ hbias, float* __restrict__ rnn,
                 int* __restrict__ tags)
{
    __shared__ float wxlds[48 * 256];   // 48KB: x2h weights, this WG's 16 cols
    __shared__ float hlds[8 * 512];     // 16KB: h(t-1)
    __shared__ float xlds[8 * 256];     // 8KB:  x(t)
    __shared__ float pad_[2304];        // ballast -> ~81.5KB -> 1 WG/CU
    __shared__ int s_rk;

    const int tid = threadIdx.x;
    ((volatile float*)pad_)[tid & 2047] = 0.f;  // keep ballast allocated

    int xcc;
    asm volatile("s_getreg_b32 %0, hwreg(HW_REG_XCC_ID)" : "=s"(xcc));
    const int g = xcc & 7;               // group = physical XCD
    if (tid == 0) {
        __threadfence();                 // one-time: drop stale/poison lines
        s_rk = atomicAdd(tags + NWG * TAGPAD + g * 16, 1); // rank in XCD
    }
    __syncthreads();
    const int rk = s_rk;
    if (rk >= 32) return;                // cannot happen with 1 WG/CU

    const int w    = tid >> 6;           // wave 0..15
    const int l    = tid & 63;           // lane
    const int cp   = w >> 1;             // column pair 0..7
    const int bh   = w & 1;              // batch half 0..1
    const int c0w  = rk * 16 + 2 * cp;   // wave's first column
    const int s0 = l & 1, s1 = (l >> 1) & 1, s2 = (l >> 2) & 1;
    const int col  = c0w + s2;                 // epilogue column (lanes l<8)
    const int ob   = 8 * g + 4 * bh + (l & 3); // epilogue batch row (global)

    // h staging map: thread stages 4 contiguous floats
    const int sb    = tid >> 7;
    const int sk    = (tid & 127) * 4;
    const int soff  = sb * 512 + sk;
    const int hsoff = (8 * g + sb) * HH + sk;
    // x staging map: thread stages 2 contiguous floats
    const int sk2   = (tid & 127) * 2;
    const int soff2 = sb * 256 + sk2;
    const int xgoff = (8 * g + sb) * II + sk2;

    // poll: lanes tid<32 poll rank-tid's tag (LLC); tid0 releases ours
    const int* tpoll = tags + ((size_t)g * 32 + (tid & 31)) * TAGPAD;
    int* tagme       = (int*)(tags + ((size_t)g * 32 + rk) * TAGPAD);

    // lane-permuted rows for cndmask-free transpose-reduce
    const int r0 = 2*s1 + s0, r1 = r0 ^ 2, r2 = r0 ^ 1, r3 = r0 ^ 3;
    const int roff0 = (4*bh + r0) * 512 + 4*l;
    const int roff1 = (4*bh + r1) * 512 + 4*l;
    const int roff2 = (4*bh + r2) * 512 + 4*l;
    const int roff3 = (4*bh + r3) * 512 + 4*l;
    const int xoff0 = (4*bh + r0) * 256 + 4*l;
    const int xoff1 = (4*bh + r1) * 256 + 4*l;
    const int xoff2 = (4*bh + r2) * 256 + 4*l;
    const int xoff3 = (4*bh + r3) * 256 + 4*l;
    // wx LDS row offsets for slot parity 0/1 (col = c0w + (parity^s2))
    const int wxA = (2*cp + s2)       * 256 + 4*l;  // parity 0
    const int wxB = (2*cp + (1 - s2)) * 256 + 4*l;  // parity 1

    // fill wxlds: rows gate*16+lc  <-  xw[(gate*512 + rk*16 + lc)][:]
    for (int idx = tid; idx < 48 * 64; idx += 1024) {
        int row = idx >> 6, c4 = (idx & 63) * 4;
        int gate = row >> 4, lc = row & 15;
        float4 v = *(const float4*)(xw + ((size_t)gate * 512 + rk * 16 + lc) * II + c4);
        *(float4*)(wxlds + row * 256 + c4) = v;
    }
    // stage x[0]
    *(float2*)(xlds + soff2) = *(const float2*)(x + xgoff);

    // h2h weights -> registers: rr=2*gate+par (slots: rr<4 -> rr, else rr+2)
    float wreg[6][8];
#pragma unroll
    for (int rr = 0; rr < 6; ++rr) {
        const float* wp = hw + ((size_t)(rr >> 1) * HH + c0w + ((rr & 1) ^ s2)) * HH;
        float4 a = *(const float4*)(wp + 4 * l);
        float4 b = *(const float4*)(wp + 256 + 4 * l);
        wreg[rr][0] = a.x; wreg[rr][1] = a.y; wreg[rr][2] = a.z; wreg[rr][3] = a.w;
        wreg[rr][4] = b.x; wreg[rr][5] = b.y; wreg[rr][6] = b.z; wreg[rr][7] = b.w;
    }
    // combined biases (r/u) + separate n-gate biases
    const float br_  = xb[col] + hbias[col];
    const float bu_  = xb[HH + col] + hbias[HH + col];
    const float bxn_ = xb[2 * HH + col];
    const float bhn_ = hbias[2 * HH + col];

    __syncthreads();   // wxlds + xlds ready

    float hloc = 0.f;            // lanes l<8: my (b,c) previous h (exact fp32)
    long long budget = 4000000;  // spin bound: bug -> wrong answer, not hang

    for (int t = 0; t < TT; ++t) {
        // prefetch x(t+1) (completes under poll/x-matvec)
        const int tn = (t + 1 < TT) ? t + 1 : TT - 1;
        const float2 xnv = *(const float2*)(x + ((size_t)tn << 14) + xgoff);

        float accA[8], accB[8], accC[8], accD[8];

        if (t > 0) {
            if (tid < 32) {  // poll the 32 group tags (LLC)
                int v;
                do {
                    asm volatile("global_load_dword %0, %1, off sc0 sc1\n\t"
                                 "s_waitcnt vmcnt(0)"
                                 : "=v"(v) : "v"(tpoll) : "memory");
                    if (v >= t) break;
                    __builtin_amdgcn_s_sleep(1);
                } while (--budget > 0);
            }
            __syncthreads(); // B1: h(t-1) complete in this XCD's L2

            // issue h(t-1) load; x-matvec below hides its L2 latency
            const float4 hv = *(const float4*)(rnn + ((size_t)(t - 1) << 15) + hsoff);

            // x-matvec: slots 0..5 = x-partials; 6,7 zeroed
            {
                float4 xv0 = *(const float4*)(xlds + xoff0);
                float4 xv1 = *(const float4*)(xlds + xoff1);
                float4 xv2 = *(const float4*)(xlds + xoff2);
                float4 xv3 = *(const float4*)(xlds + xoff3);
#pragma unroll
                for (int s = 0; s < 6; ++s) {
                    const float* wp = wxlds + (s >> 1) * 4096 + ((s & 1) ? wxB : wxA);
                    float4 wx = *(const float4*)wp;
                    accA[s] = fmaf(xv0.w, wx.w, fmaf(xv0.z, wx.z, fmaf(xv0.y, wx.y, xv0.x * wx.x)));
                    accB[s] = fmaf(xv1.w, wx.w, fmaf(xv1.z, wx.z, fmaf(xv1.y, wx.y, xv1.x * wx.x)));
                    accC[s] = fmaf(xv2.w, wx.w, fmaf(xv2.z, wx.z, fmaf(xv2.y, wx.y, xv2.x * wx.x)));
                    accD[s] = fmaf(xv3.w, wx.w, fmaf(xv3.z, wx.z, fmaf(xv3.y, wx.y, xv3.x * wx.x)));
                }
                accA[6] = 0.f; accA[7] = 0.f; accB[6] = 0.f; accB[7] = 0.f;
                accC[6] = 0.f; accC[7] = 0.f; accD[6] = 0.f; accD[7] = 0.f;
            }
            *(float4*)(hlds + soff) = hv;   // compiler inserts vmcnt wait here
            __syncthreads(); // B2: h staged

            *(float2*)(xlds + soff2) = xnv; // restage x(t+1); reads were pre-B2

            // h-matvec per row (<=8 h regs live): r/u into slots 0..3; n into 6,7
            {
                float4 hA = *(const float4*)(hlds + roff0);
                float4 hB = *(const float4*)(hlds + roff0 + 256);
#pragma unroll
                for (int rr = 0; rr < 4; ++rr) {
                    float a = accA[rr];
                    a = fmaf(hA.x, wreg[rr][0], a); a = fmaf(hA.y, wreg[rr][1], a);
                    a = fmaf(hA.z, wreg[rr][2], a); a = fmaf(hA.w, wreg[rr][3], a);
                    a = fmaf(hB.x, wreg[rr][4], a); a = fmaf(hB.y, wreg[rr][5], a);
                    a = fmaf(hB.z, wreg[rr][6], a); a = fmaf(hB.w, wreg[rr][7], a);
                    accA[rr] = a;
                }
#pragma unroll
                for (int rr = 4; rr < 6; ++rr) {
                    float a = accA[rr + 2];
                    a = fmaf(hA.x, wreg[rr][0], a); a = fmaf(hA.y, wreg[rr][1], a);
                    a = fmaf(hA.z, wreg[rr][2], a); a = fmaf(hA.w, wreg[rr][3], a);
                    a = fmaf(hB.x, wreg[rr][4], a); a = fmaf(hB.y, wreg[rr][5], a);
                    a = fmaf(hB.z, wreg[rr][6], a); a = fmaf(hB.w, wreg[rr][7], a);
                    accA[rr + 2] = a;
                }
            }
            {
                float4 hA = *(const float4*)(hlds + roff1);
                float4 hB = *(const float4*)(hlds + roff1 + 256);
#pragma unroll
                for (int rr = 0; rr < 4; ++rr) {
                    float a = accB[rr];
                    a = fmaf(hA.x, wreg[rr][0], a); a = fmaf(hA.y, wreg[rr][1], a);
                    a = fmaf(hA.z, wreg[rr][2], a); a = fmaf(hA.w, wreg[rr][3], a);
                    a = fmaf(hB.x, wreg[rr][4], a); a = fmaf(hB.y, wreg[rr][5], a);
                    a = fmaf(hB.z, wreg[rr][6], a); a = fmaf(hB.w, wreg[rr][7], a);
                    accB[rr] = a;
                }
#pragma unroll
                for (int rr = 4; rr < 6; ++rr) {
                    float a = accB[rr + 2];
                    a = fmaf(hA.x, wreg[rr][0], a); a = fmaf(hA.y, wreg[rr][1], a);
                    a = fmaf(hA.z, wreg[rr][2], a); a = fmaf(hA.w, wreg[rr][3], a);
                    a = fmaf(hB.x, wreg[rr][4], a); a = fmaf(hB.y, wreg[rr][5], a);
                    a = fmaf(hB.z, wreg[rr][6], a); a = fmaf(hB.w, wreg[rr][7], a);
                    accB[rr + 2] = a;
                }
            }
            {
                float4 hA = *(const float4*)(hlds + roff2);
                float4 hB = *(const float4*)(hlds + roff2 + 256);
#pragma unroll
                for (int rr = 0; rr < 4; ++rr) {
                    float a = accC[rr];
                    a = fmaf(hA.x, wreg[rr][0], a); a = fmaf(hA.y, wreg[rr][1], a);
                    a = fmaf(hA.z, wreg[rr][2], a); a = fmaf(hA.w, wreg[rr][3], a);
                    a = fmaf(hB.x, wreg[rr][4], a); a = fmaf(hB.y, wreg[rr][5], a);
                    a = fmaf(hB.z, wreg[rr][6], a); a = fmaf(hB.w, wreg[rr][7], a);
                    accC[rr] = a;
                }
#pragma unroll
                for (int rr = 4; rr < 6; ++rr) {
                    float a = accC[rr + 2];
                    a = fmaf(hA.x, wreg[rr][0], a); a = fmaf(hA.y, wreg[rr][1], a);
                    a = fmaf(hA.z, wreg[rr][2], a); a = fmaf(hA.w, wreg[rr][3], a);
                    a = fmaf(hB.x, wreg[rr][4], a); a = fmaf(hB.y, wreg[rr][5], a);
                    a = fmaf(hB.z, wreg[rr][6], a); a = fmaf(hB.w, wreg[rr][7], a);
                    accC[rr + 2] = a;
                }
            }
            {
                float4 hA = *(const float4*)(hlds + roff3);
                float4 hB = *(const float4*)(hlds + roff3 + 256);
#pragma unroll
                for (int rr = 0; rr < 4; ++rr) {
                    float a = accD[rr];
                    a = fmaf(hA.x, wreg[rr][0], a); a = fmaf(hA.y, wreg[rr][1], a);
                    a = fmaf(hA.z, wreg[rr][2], a); a = fmaf(hA.w, wreg[rr][3], a);
                    a = fmaf(hB.x, wreg[rr][4], a); a = fmaf(hB.y, wreg[rr][5], a);
                    a = fmaf(hB.z, wreg[rr][6], a); a = fmaf(hB.w, wreg[rr][7], a);
                    accD[rr] = a;
                }
#pragma unroll
                for (int rr = 4; rr < 6; ++rr) {
                    float a = accD[rr + 2];
                    a = fmaf(hA.x, wreg[rr][0], a); a = fmaf(hA.y, wreg[rr][1], a);
                    a = fmaf(hA.z, wreg[rr][2], a); a = fmaf(hA.w, wreg[rr][3], a);
                    a = fmaf(hB.x, wreg[rr][4], a); a = fmaf(hB.y, wreg[rr][5], a);
                    a = fmaf(hB.z, wreg[rr][6], a); a = fmaf(hB.w, wreg[rr][7], a);
                    accD[rr + 2] = a;
                }
            }
        } else {
            // t=0: x-matvec only (h0 = 0)
            float4 xv0 = *(const float4*)(xlds + xoff0);
            float4 xv1 = *(const float4*)(xlds + xoff1);
            float4 xv2 = *(const float4*)(xlds + xoff2);
            float4 xv3 = *(const float4*)(xlds + xoff3);
#pragma unroll
            for (int s = 0; s < 6; ++s) {
                const float* wp = wxlds + (s >> 1) * 4096 + ((s & 1) ? wxB : wxA);
                float4 wx = *(const float4*)wp;
                accA[s] = fmaf(xv0.w, wx.w, fmaf(xv0.z, wx.z, fmaf(xv0.y, wx.y, xv0.x * wx.x)));
                accB[s] = fmaf(xv1.w, wx.w, fmaf(xv1.z, wx.z, fmaf(xv1.y, wx.y, xv1.x * wx.x)));
                accC[s] = fmaf(xv2.w, wx.w, fmaf(xv2.z, wx.z, fmaf(xv2.y, wx.y, xv2.x * wx.x)));
                accD[s] = fmaf(xv3.w, wx.w, fmaf(xv3.z, wx.z, fmaf(xv3.y, wx.y, xv3.x * wx.x)));
            }
            accA[6] = 0.f; accA[7] = 0.f; accB[6] = 0.f; accB[7] = 0.f;
            accC[6] = 0.f; accC[7] = 0.f; accD[6] = 0.f; accD[7] = 0.f;
            __syncthreads();                // xlds reads done
            *(float2*)(xlds + soff2) = xnv; // restage x(1)
        }

        // single 8-slot cndmask-free transpose-reduce
        float t0[8], t1[8], a2v[8], a3[4];
#pragma unroll
        for (int s = 0; s < 8; ++s) {
            t0[s] = accA[s] + xor1_dpp(accC[s]);
            t1[s] = accB[s] + xor1_dpp(accD[s]);
        }
#pragma unroll
        for (int s = 0; s < 8; ++s)
            a2v[s] = t0[s] + xor2_dpp(t1[s]);
#pragma unroll
        for (int gi = 0; gi < 4; ++gi)
            a3[gi] = a2v[2*gi] + __shfl_xor(a2v[2*gi + 1], 4, 64);
#pragma unroll
        for (int gi = 0; gi < 4; ++gi) {
            a3[gi] += __shfl_xor(a3[gi], 8, 64);
            a3[gi] += __shfl_xor(a3[gi], 16, 64);
            a3[gi] += __shfl_xor(a3[gi], 32, 64);
        }

        if (l < 8) { // one lane per output (b=ob, c=col)
            float rg = 1.f / (1.f + __expf(-(a3[0] + br_)));
            float ug = 1.f / (1.f + __expf(-(a3[1] + bu_)));
            // h2h bias of n-gate sits INSIDE reset*(...), per reference
            float npre = (a3[2] + bxn_) + rg * (a3[3] + bhn_);
            float e  = __expf(-2.f * npre);
            float nv = 2.f / (1.f + e) - 1.f;
            float hy = ug * hloc + (1.f - ug) * nv;
            hloc = hy;
            float* dstp = rnn + ((size_t)t << 15) + ob * HH + col;
            // plain store: write-through into this XCD's L2
            asm volatile("global_store_dword %0, %1, off"
                         :: "v"(dstp), "v"(hy) : "memory");
        }
        asm volatile("s_waitcnt vmcnt(0)" ::: "memory"); // h stores drained
        __syncthreads(); // B3: all waves' stores + xlds restage complete
        if (tid == 0) {
            int tv = t + 1;
            asm volatile("global_store_dword %0, %1, off sc0 sc1"
                         :: "v"(tagme), "v"(tv) : "memory");
        }
    }
}

// ---------------- Phase C: fc output (unchanged) ----------------
__global__ __launch_bounds__(256)
void fc_kernel(const float* __restrict__ rnn, const float* __restrict__ fcw,
               const float* __restrict__ fcb, float* __restrict__ out)
{
    __shared__ float wlds[128][65];
    const int t = blockIdx.x;
    const int tid = threadIdx.x;
    const int o  = tid & 63;
    const int bg = tid >> 6;
    float acc[16];
#pragma unroll
    for (int i = 0; i < 16; ++i) acc[i] = 0.f;

    for (int kc = 0; kc < 4; ++kc) {
        const int k0 = kc * 128;
        __syncthreads();
        for (int idx = tid; idx < 64 * 32; idx += 256) {
            int oo = idx >> 5, kq = (idx & 31) * 4;
            float4 v = *(const float4*)(fcw + (size_t)oo * HH + k0 + kq);
            wlds[kq][oo] = v.x; wlds[kq+1][oo] = v.y;
            wlds[kq+2][oo] = v.z; wlds[kq+3][oo] = v.w;
        }
        __syncthreads();
#pragma unroll 2
        for (int k4 = 0; k4 < 32; ++k4) {
            float w0 = wlds[k4*4+0][o], w1 = wlds[k4*4+1][o];
            float w2 = wlds[k4*4+2][o], w3 = wlds[k4*4+3][o];
#pragma unroll
            for (int i = 0; i < 16; ++i) {
                int bb = bg * 16 + i;
                float4 h4 = *(const float4*)(rnn + ((size_t)t * BB + bb) * HH + k0 + k4*4);
                acc[i] = fmaf(h4.x, w0, fmaf(h4.y, w1, fmaf(h4.z, w2, fmaf(h4.w, w3, acc[i]))));
            }
        }
    }
    float bo = fcb[o];
#pragma unroll
    for (int i = 0; i < 16; ++i) {
        int bb = bg * 16 + i;
        out[((size_t)t * BB + bb) * OO + o] = acc[i] + bo;
    }
}

extern "C" void kernel_launch(void* const* d_in, const int* in_sizes, int n_in,
                              void* d_out, int out_size, void* d_ws, size_t ws_size,
                              hipStream_t stream)
{
    const float* x     = (const float*)d_in[0];
    const float* x2h_w = (const float*)d_in[1];
    const float* x2h_b = (const float*)d_in[2];
    const float* h2h_w = (const float*)d_in[3];
    const float* h2h_b = (const float*)d_in[4];
    const float* fc_w  = (const float*)d_in[5];
    const float* fc_b  = (const float*)d_in[6];

    float* out = (float*)d_out;                        // [T][B][O]
    float* rnn = (float*)d_out + (size_t)TT * BB * OO; // [T][B][H]

    int* tags = (int*)d_ws;                            // 256 WG tags + rank ctrs

    hipMemsetAsync(tags, 0, (NWG * TAGPAD + 8 * 16) * sizeof(int), stream);

    scan_kernel<<<NWG, 1024, 0, stream>>>(x, x2h_w, x2h_b, h2h_w, h2h_b, rnn, tags);
    fc_kernel<<<TT, 256, 0, stream>>>(rnn, fc_w, fc_b, out);
}

// Round 10
// 8077.422 us; speedup vs baseline: 2.0691x; 1.0246x over previous
//
#include <hip/hip_runtime.h>
#include <cstdint>
#include <cstddef>

#define TT 512
#define BB 64
#define II 256
#define HH 512
#define OO 64
#define NWG 256   // scan workgroups: one per CU (forced by LDS footprint)
#define TAGPAD 16 // dwords between tags (64B -> distinct LLC lines)

// DPP quad-perm cross-lane adds (VALU, not LDS pipe):
// xor1: perm [1,0,3,2] = 0xB1 ; xor2: perm [2,3,0,1] = 0x4E
__device__ __forceinline__ float xor1_dpp(float v) {
    return __int_as_float(__builtin_amdgcn_update_dpp(
        0, __float_as_int(v), 0xB1, 0xF, 0xF, true));
}
__device__ __forceinline__ float xor2_dpp(float v) {
    return __int_as_float(__builtin_amdgcn_update_dpp(
        0, __float_as_int(v), 0x4E, 0xF, 0xF, true));
}

// ---------------- Fused x-proj + XCD-local persistent GRU scan -----------
// r9 algorithm, UNCHANGED, with the register cap lifted:
// __launch_bounds__(1024, 1): hipcc interpreted (1024,4) as 4 blocks/CU ->
// 8 waves/SIMD plan -> 64-VGPR cap -> 40 regs of live state spilled to
// scratch (r8: 46GB, r9: 20GB FETCH). (1024,1) -> 16 waves/CU -> 128-VGPR
// budget; the 83KB LDS ballast already forces 1 WG/CU, so occupancy is
// identical by construction.
//  * SINGLE combined 8-slot reduce {r,u,x_n,h_n}x2cols (slots 0,1=r; 2,3=u;
//    4,5=x_n; 6,7=h_n); x/h partials for r,u summed pre-reduce.
//  * h(t-1) global load issued before the x-matvec (L2 latency hidden).
// Tags LLC-scope sc0 sc1 (round-3 lesson). Lane-permuted rows
// (r0=2s1+s0, r1=r0^2, r2=r0^1, r3=r0^3; weight col ^s2) -> cndmask-free.
__global__ __launch_bounds__(1024, 1)
void scan_kernel(const float* __restrict__ x,  const float* __restrict__ xw,
                 const float* __restrict__ xb, const float* __restrict__ hw,
                 const float* __restrict__ hbias, float* __restrict__ rnn,
                 int* __restrict__ tags)
{
    __shared__ float wxlds[48 * 256];   // 48KB: x2h weights, this WG's 16 cols
    __shared__ float hlds[8 * 512];     // 16KB: h(t-1)
    __shared__ float xlds[8 * 256];     // 8KB:  x(t)
    __shared__ float pad_[2304];        // ballast -> ~81.5KB -> 1 WG/CU
    __shared__ int s_rk;

    const int tid = threadIdx.x;
    ((volatile float*)pad_)[tid & 2047] = 0.f;  // keep ballast allocated

    int xcc;
    asm volatile("s_getreg_b32 %0, hwreg(HW_REG_XCC_ID)" : "=s"(xcc));
    const int g = xcc & 7;               // group = physical XCD
    if (tid == 0) {
        __threadfence();                 // one-time: drop stale/poison lines
        s_rk = atomicAdd(tags + NWG * TAGPAD + g * 16, 1); // rank in XCD
    }
    __syncthreads();
    const int rk = s_rk;
    if (rk >= 32) return;                // cannot happen with 1 WG/CU

    const int w    = tid >> 6;           // wave 0..15
    const int l    = tid & 63;           // lane
    const int cp   = w >> 1;             // column pair 0..7
    const int bh   = w & 1;              // batch half 0..1
    const int c0w  = rk * 16 + 2 * cp;   // wave's first column
    const int s0 = l & 1, s1 = (l >> 1) & 1, s2 = (l >> 2) & 1;
    const int col  = c0w + s2;                 // epilogue column (lanes l<8)
    const int ob   = 8 * g + 4 * bh + (l & 3); // epilogue batch row (global)

    // h staging map: thread stages 4 contiguous floats
    const int sb    = tid >> 7;
    const int sk    = (tid & 127) * 4;
    const int soff  = sb * 512 + sk;
    const int hsoff = (8 * g + sb) * HH + sk;
    // x staging map: thread stages 2 contiguous floats
    const int sk2   = (tid & 127) * 2;
    const int soff2 = sb * 256 + sk2;
    const int xgoff = (8 * g + sb) * II + sk2;

    // poll: lanes tid<32 poll rank-tid's tag (LLC); tid0 releases ours
    const int* tpoll = tags + ((size_t)g * 32 + (tid & 31)) * TAGPAD;
    int* tagme       = (int*)(tags + ((size_t)g * 32 + rk) * TAGPAD);

    // lane-permuted rows for cndmask-free transpose-reduce
    const int r0 = 2*s1 + s0, r1 = r0 ^ 2, r2 = r0 ^ 1, r3 = r0 ^ 3;
    const int roff0 = (4*bh + r0) * 512 + 4*l;
    const int roff1 = (4*bh + r1) * 512 + 4*l;
    const int roff2 = (4*bh + r2) * 512 + 4*l;
    const int roff3 = (4*bh + r3) * 512 + 4*l;
    const int xoff0 = (4*bh + r0) * 256 + 4*l;
    const int xoff1 = (4*bh + r1) * 256 + 4*l;
    const int xoff2 = (4*bh + r2) * 256 + 4*l;
    const int xoff3 = (4*bh + r3) * 256 + 4*l;
    // wx LDS row offsets for slot parity 0/1 (col = c0w + (parity^s2))
    const int wxA = (2*cp + s2)       * 256 + 4*l;  // parity 0
    const int wxB = (2*cp + (1 - s2)) * 256 + 4*l;  // parity 1

    // fill wxlds: rows gate*16+lc  <-  xw[(gate*512 + rk*16 + lc)][:]
    for (int idx = tid; idx < 48 * 64; idx += 1024) {
        int row = idx >> 6, c4 = (idx & 63) * 4;
        int gate = row >> 4, lc = row & 15;
        float4 v = *(const float4*)(xw + ((size_t)gate * 512 + rk * 16 + lc) * II + c4);
        *(float4*)(wxlds + row * 256 + c4) = v;
    }
    // stage x[0]
    *(float2*)(xlds + soff2) = *(const float2*)(x + xgoff);

    // h2h weights -> registers: rr=2*gate+par (slots: rr<4 -> rr, else rr+2)
    float wreg[6][8];
#pragma unroll
    for (int rr = 0; rr < 6; ++rr) {
        const float* wp = hw + ((size_t)(rr >> 1) * HH + c0w + ((rr & 1) ^ s2)) * HH;
        float4 a = *(const float4*)(wp + 4 * l);
        float4 b = *(const float4*)(wp + 256 + 4 * l);
        wreg[rr][0] = a.x; wreg[rr][1] = a.y; wreg[rr][2] = a.z; wreg[rr][3] = a.w;
        wreg[rr][4] = b.x; wreg[rr][5] = b.y; wreg[rr][6] = b.z; wreg[rr][7] = b.w;
    }
    // combined biases (r/u) + separate n-gate biases
    const float br_  = xb[col] + hbias[col];
    const float bu_  = xb[HH + col] + hbias[HH + col];
    const float bxn_ = xb[2 * HH + col];
    const float bhn_ = hbias[2 * HH + col];

    __syncthreads();   // wxlds + xlds ready

    float hloc = 0.f;            // lanes l<8: my (b,c) previous h (exact fp32)
    long long budget = 4000000;  // spin bound: bug -> wrong answer, not hang

    for (int t = 0; t < TT; ++t) {
        // prefetch x(t+1) (completes under poll/x-matvec)
        const int tn = (t + 1 < TT) ? t + 1 : TT - 1;
        const float2 xnv = *(const float2*)(x + ((size_t)tn << 14) + xgoff);

        float accA[8], accB[8], accC[8], accD[8];

        if (t > 0) {
            if (tid < 32) {  // poll the 32 group tags (LLC)
                int v;
                do {
                    asm volatile("global_load_dword %0, %1, off sc0 sc1\n\t"
                                 "s_waitcnt vmcnt(0)"
                                 : "=v"(v) : "v"(tpoll) : "memory");
                    if (v >= t) break;
                    __builtin_amdgcn_s_sleep(1);
                } while (--budget > 0);
            }
            __syncthreads(); // B1: h(t-1) complete in this XCD's L2

            // issue h(t-1) load; x-matvec below hides its L2 latency
            const float4 hv = *(const float4*)(rnn + ((size_t)(t - 1) << 15) + hsoff);

            // x-matvec: slots 0..5 = x-partials; 6,7 zeroed
            {
                float4 xv0 = *(const float4*)(xlds + xoff0);
                float4 xv1 = *(const float4*)(xlds + xoff1);
                float4 xv2 = *(const float4*)(xlds + xoff2);
                float4 xv3 = *(const float4*)(xlds + xoff3);
#pragma unroll
                for (int s = 0; s < 6; ++s) {
                    const float* wp = wxlds + (s >> 1) * 4096 + ((s & 1) ? wxB : wxA);
                    float4 wx = *(const float4*)wp;
                    accA[s] = fmaf(xv0.w, wx.w, fmaf(xv0.z, wx.z, fmaf(xv0.y, wx.y, xv0.x * wx.x)));
                    accB[s] = fmaf(xv1.w, wx.w, fmaf(xv1.z, wx.z, fmaf(xv1.y, wx.y, xv1.x * wx.x)));
                    accC[s] = fmaf(xv2.w, wx.w, fmaf(xv2.z, wx.z, fmaf(xv2.y, wx.y, xv2.x * wx.x)));
                    accD[s] = fmaf(xv3.w, wx.w, fmaf(xv3.z, wx.z, fmaf(xv3.y, wx.y, xv3.x * wx.x)));
                }
                accA[6] = 0.f; accA[7] = 0.f; accB[6] = 0.f; accB[7] = 0.f;
                accC[6] = 0.f; accC[7] = 0.f; accD[6] = 0.f; accD[7] = 0.f;
            }
            *(float4*)(hlds + soff) = hv;   // compiler inserts vmcnt wait here
            __syncthreads(); // B2: h staged

            *(float2*)(xlds + soff2) = xnv; // restage x(t+1); reads were pre-B2

            // h-matvec per row (<=8 h regs live): r/u into slots 0..3; n into 6,7
            {
                float4 hA = *(const float4*)(hlds + roff0);
                float4 hB = *(const float4*)(hlds + roff0 + 256);
#pragma unroll
                for (int rr = 0; rr < 4; ++rr) {
                    float a = accA[rr];
                    a = fmaf(hA.x, wreg[rr][0], a); a = fmaf(hA.y, wreg[rr][1], a);
                    a = fmaf(hA.z, wreg[rr][2], a); a = fmaf(hA.w, wreg[rr][3], a);
                    a = fmaf(hB.x, wreg[rr][4], a); a = fmaf(hB.y, wreg[rr][5], a);
                    a = fmaf(hB.z, wreg[rr][6], a); a = fmaf(hB.w, wreg[rr][7], a);
                    accA[rr] = a;
                }
#pragma unroll
                for (int rr = 4; rr < 6; ++rr) {
                    float a = accA[rr + 2];
                    a = fmaf(hA.x, wreg[rr][0], a); a = fmaf(hA.y, wreg[rr][1], a);
                    a = fmaf(hA.z, wreg[rr][2], a); a = fmaf(hA.w, wreg[rr][3], a);
                    a = fmaf(hB.x, wreg[rr][4], a); a = fmaf(hB.y, wreg[rr][5], a);
                    a = fmaf(hB.z, wreg[rr][6], a); a = fmaf(hB.w, wreg[rr][7], a);
                    accA[rr + 2] = a;
                }
            }
            {
                float4 hA = *(const float4*)(hlds + roff1);
                float4 hB = *(const float4*)(hlds + roff1 + 256);
#pragma unroll
                for (int rr = 0; rr < 4; ++rr) {
                    float a = accB[rr];
                    a = fmaf(hA.x, wreg[rr][0], a); a = fmaf(hA.y, wreg[rr][1], a);
                    a = fmaf(hA.z, wreg[rr][2], a); a = fmaf(hA.w, wreg[rr][3], a);
                    a = fmaf(hB.x, wreg[rr][4], a); a = fmaf(hB.y, wreg[rr][5], a);
                    a = fmaf(hB.z, wreg[rr][6], a); a = fmaf(hB.w, wreg[rr][7], a);
                    accB[rr] = a;
                }
#pragma unroll
                for (int rr = 4; rr < 6; ++rr) {
                    float a = accB[rr + 2];
                    a = fmaf(hA.x, wreg[rr][0], a); a = fmaf(hA.y, wreg[rr][1], a);
                    a = fmaf(hA.z, wreg[rr][2], a); a = fmaf(hA.w, wreg[rr][3], a);
                    a = fmaf(hB.x, wreg[rr][4], a); a = fmaf(hB.y, wreg[rr][5], a);
                    a = fmaf(hB.z, wreg[rr][6], a); a = fmaf(hB.w, wreg[rr][7], a);
                    accB[rr + 2] = a;
                }
            }
            {
                float4 hA = *(const float4*)(hlds + roff2);
                float4 hB = *(const float4*)(hlds + roff2 + 256);
#pragma unroll
                for (int rr = 0; rr < 4; ++rr) {
                    float a = accC[rr];
                    a = fmaf(hA.x, wreg[rr][0], a); a = fmaf(hA.y, wreg[rr][1], a);
                    a = fmaf(hA.z, wreg[rr][2], a); a = fmaf(hA.w, wreg[rr][3], a);
                    a = fmaf(hB.x, wreg[rr][4], a); a = fmaf(hB.y, wreg[rr][5], a);
                    a = fmaf(hB.z, wreg[rr][6], a); a = fmaf(hB.w, wreg[rr][7], a);
                    accC[rr] = a;
                }
#pragma unroll
                for (int rr = 4; rr < 6; ++rr) {
                    float a = accC[rr + 2];
                    a = fmaf(hA.x, wreg[rr][0], a); a = fmaf(hA.y, wreg[rr][1], a);
                    a = fmaf(hA.z, wreg[rr][2], a); a = fmaf(hA.w, wreg[rr][3], a);
                    a = fmaf(hB.x, wreg[rr][4], a); a = fmaf(hB.y, wreg[rr][5], a);
                    a = fmaf(hB.z, wreg[rr][6], a); a = fmaf(hB.w, wreg[rr][7], a);
                    accC[rr + 2] = a;
                }
            }
            {
                float4 hA = *(const float4*)(hlds + roff3);
                float4 hB = *(const float4*)(hlds + roff3 + 256);
#pragma unroll
                for (int rr = 0; rr < 4; ++rr) {
                    float a = accD[rr];
                    a = fmaf(hA.x, wreg[rr][0], a); a = fmaf(hA.y, wreg[rr][1], a);
                    a = fmaf(hA.z, wreg[rr][2], a); a = fmaf(hA.w, wreg[rr][3], a);
                    a = fmaf(hB.x, wreg[rr][4], a); a = fmaf(hB.y, wreg[rr][5], a);
                    a = fmaf(hB.z, wreg[rr][6], a); a = fmaf(hB.w, wreg[rr][7], a);
                    accD[rr] = a;
                }
#pragma unroll
                for (int rr = 4; rr < 6; ++rr) {
                    float a = accD[rr + 2];
                    a = fmaf(hA.x, wreg[rr][0], a); a = fmaf(hA.y, wreg[rr][1], a);
                    a = fmaf(hA.z, wreg[rr][2], a); a = fmaf(hA.w, wreg[rr][3], a);
                    a = fmaf(hB.x, wreg[rr][4], a); a = fmaf(hB.y, wreg[rr][5], a);
                    a = fmaf(hB.z, wreg[rr][6], a); a = fmaf(hB.w, wreg[rr][7], a);
                    accD[rr + 2] = a;
                }
            }
        } else {
            // t=0: x-matvec only (h0 = 0)
            float4 xv0 = *(const float4*)(xlds + xoff0);
            float4 xv1 = *(const float4*)(xlds + xoff1);
            float4 xv2 = *(const float4*)(xlds + xoff2);
            float4 xv3 = *(const float4*)(xlds + xoff3);
#pragma unroll
            for (int s = 0; s < 6; ++s) {
                const float* wp = wxlds + (s >> 1) * 4096 + ((s & 1) ? wxB : wxA);
                float4 wx = *(const float4*)wp;
                accA[s] = fmaf(xv0.w, wx.w, fmaf(xv0.z, wx.z, fmaf(xv0.y, wx.y, xv0.x * wx.x)));
                accB[s] = fmaf(xv1.w, wx.w, fmaf(xv1.z, wx.z, fmaf(xv1.y, wx.y, xv1.x * wx.x)));
                accC[s] = fmaf(xv2.w, wx.w, fmaf(xv2.z, wx.z, fmaf(xv2.y, wx.y, xv2.x * wx.x)));
                accD[s] = fmaf(xv3.w, wx.w, fmaf(xv3.z, wx.z, fmaf(xv3.y, wx.y, xv3.x * wx.x)));
            }
            accA[6] = 0.f; accA[7] = 0.f; accB[6] = 0.f; accB[7] = 0.f;
            accC[6] = 0.f; accC[7] = 0.f; accD[6] = 0.f; accD[7] = 0.f;
            __syncthreads();                // xlds reads done
            *(float2*)(xlds + soff2) = xnv; // restage x(1)
        }

        // single 8-slot cndmask-free transpose-reduce
        float t0[8], t1[8], a2v[8], a3[4];
#pragma unroll
        for (int s = 0; s < 8; ++s) {
            t0[s] = accA[s] + xor1_dpp(accC[s]);
            t1[s] = accB[s] + xor1_dpp(accD[s]);
        }
#pragma unroll
        for (int s = 0; s < 8; ++s)
            a2v[s] = t0[s] + xor2_dpp(t1[s]);
#pragma unroll
        for (int gi = 0; gi < 4; ++gi)
            a3[gi] = a2v[2*gi] + __shfl_xor(a2v[2*gi + 1], 4, 64);
#pragma unroll
        for (int gi = 0; gi < 4; ++gi) {
            a3[gi] += __shfl_xor(a3[gi], 8, 64);
            a3[gi] += __shfl_xor(a3[gi], 16, 64);
            a3[gi] += __shfl_xor(a3[gi], 32, 64);
        }

        if (l < 8) { // one lane per output (b=ob, c=col)
            float rg = 1.f / (1.f + __expf(-(a3[0] + br_)));
            float ug = 1.f / (1.f + __expf(-(a3[1] + bu_)));
            // h2h bias of n-gate sits INSIDE reset*(...), per reference
            float npre = (a3[2] + bxn_) + rg * (a3[3] + bhn_);
            float e  = __expf(-2.f * npre);
            float nv = 2.f / (1.f + e) - 1.f;
            float hy = ug * hloc + (1.f - ug) * nv;
            hloc = hy;
            float* dstp = rnn + ((size_t)t << 15) + ob * HH + col;
            // plain store: write-through into this XCD's L2
            asm volatile("global_store_dword %0, %1, off"
                         :: "v"(dstp), "v"(hy) : "memory");
        }
        asm volatile("s_waitcnt vmcnt(0)" ::: "memory"); // h stores drained
        __syncthreads(); // B3: all waves' stores + xlds restage complete
        if (tid == 0) {
            int tv = t + 1;
            asm volatile("global_store_dword %0, %1, off sc0 sc1"
                         :: "v"(tagme), "v"(tv) : "memory");
        }
    }
}

// ---------------- Phase C: fc output (unchanged) ----------------
__global__ __launch_bounds__(256)
void fc_kernel(const float* __restrict__ rnn, const float* __restrict__ fcw,
               const float* __restrict__ fcb, float* __restrict__ out)
{
    __shared__ float wlds[128][65];
    const int t = blockIdx.x;
    const int tid = threadIdx.x;
    const int o  = tid & 63;
    const int bg = tid >> 6;
    float acc[16];
#pragma unroll
    for (int i = 0; i < 16; ++i) acc[i] = 0.f;

    for (int kc = 0; kc < 4; ++kc) {
        const int k0 = kc * 128;
        __syncthreads();
        for (int idx = tid; idx < 64 * 32; idx += 256) {
            int oo = idx >> 5, kq = (idx & 31) * 4;
            float4 v = *(const float4*)(fcw + (size_t)oo * HH + k0 + kq);
            wlds[kq][oo] = v.x; wlds[kq+1][oo] = v.y;
            wlds[kq+2][oo] = v.z; wlds[kq+3][oo] = v.w;
        }
        __syncthreads();
#pragma unroll 2
        for (int k4 = 0; k4 < 32; ++k4) {
            float w0 = wlds[k4*4+0][o], w1 = wlds[k4*4+1][o];
            float w2 = wlds[k4*4+2][o], w3 = wlds[k4*4+3][o];
#pragma unroll
            for (int i = 0; i < 16; ++i) {
                int bb = bg * 16 + i;
                float4 h4 = *(const float4*)(rnn + ((size_t)t * BB + bb) * HH + k0 + k4*4);
                acc[i] = fmaf(h4.x, w0, fmaf(h4.y, w1, fmaf(h4.z, w2, fmaf(h4.w, w3, acc[i]))));
            }
        }
    }
    float bo = fcb[o];
#pragma unroll
    for (int i = 0; i < 16; ++i) {
        int bb = bg * 16 + i;
        out[((size_t)t * BB + bb) * OO + o] = acc[i] + bo;
    }
}

extern "C" void kernel_launch(void* const* d_in, const int* in_sizes, int n_in,
                              void* d_out, int out_size, void* d_ws, size_t ws_size,
                              hipStream_t stream)
{
    const float* x     = (const float*)d_in[0];
    const float* x2h_w = (const float*)d_in[1];
    const float* x2h_b = (const float*)d_in[2];
    const float* h2h_w = (const float*)d_in[3];
    const float* h2h_b = (const float*)d_in[4];
    const float* fc_w  = (const float*)d_in[5];
    const float* fc_b  = (const float*)d_in[6];

    float* out = (float*)d_out;                        // [T][B][O]
    float* rnn = (float*)d_out + (size_t)TT * BB * OO; // [T][B][H]

    int* tags = (int*)d_ws;                            // 256 WG tags + rank ctrs

    hipMemsetAsync(tags, 0, (NWG * TAGPAD + 8 * 16) * sizeof(int), stream);

    scan_kernel<<<NWG, 1024, 0, stream>>>(x, x2h_w, x2h_b, h2h_w, h2h_b, rnn, tags);
    fc_kernel<<<TT, 256, 0, stream>>>(rnn, fc_w, fc_b, out);
}

// Round 11
// 5547.635 us; speedup vs baseline: 3.0126x; 1.4560x over previous
//
#include <hip/hip_runtime.h>
#include <cstdint>
#include <cstddef>

#define TT 512
#define BB 64
#define II 256
#define HH 512
#define OO 64
#define NWG 256   // scan workgroups: one per CU (forced by LDS footprint)
#define TAGPAD 16 // dwords between tags (64B -> distinct LLC lines)

// DPP quad-perm cross-lane adds (VALU, not LDS pipe):
// xor1: perm [1,0,3,2] = 0xB1 ; xor2: perm [2,3,0,1] = 0x4E
__device__ __forceinline__ float xor1_dpp(float v) {
    return __int_as_float(__builtin_amdgcn_update_dpp(
        0, __float_as_int(v), 0xB1, 0xF, 0xF, true));
}
__device__ __forceinline__ float xor2_dpp(float v) {
    return __int_as_float(__builtin_amdgcn_update_dpp(
        0, __float_as_int(v), 0x4E, 0xF, 0xF, true));
}

// ---------------- Fused x-proj + XCD-local persistent GRU scan -----------
// r7 structure (proven spill-free): x-matvec+round1/2 pre-poll, poll, B1,
// stage h, B2, h-matvec+round1/2, tail, epilogue, drain, B3, release.
// Register discipline (r8-r10 lesson): accumulator arrays are born and die
// within one barrier region; ONLY a2x[6] scalars cross barriers. No 2-D
// arrays, no conditional indices, no acc state across LDS writes.
// New vs r7:
//  * SHARED reduce tail: both reduces stop at round-2 (a2x[6], a2h[6]);
//    one combined 8-slot tail {r,u,x_n,h_n} -> 16 shfl vs r7's 24.
//    (round-2 partials have identical lane structure for x and h; r/u
//    slots sum pre-sigmoid, n keeps x/h split for the reset factor.)
//  * explicit amdgpu_waves_per_eu(4,4): exactly 16 waves/CU (1 WG/CU is
//    LDS-forced) -> states the 128-VGPR budget directly to the backend.
// Tags LLC-scope sc0 sc1 (round-3 lesson). Lane-permuted rows
// (r0=2s1+s0, r1=r0^2, r2=r0^1, r3=r0^3; weight col ^s2) -> cndmask-free.
__global__ __attribute__((amdgpu_flat_work_group_size(1024, 1024)))
__attribute__((amdgpu_waves_per_eu(4, 4)))
void scan_kernel(const float* __restrict__ x,  const float* __restrict__ xw,
                 const float* __restrict__ xb, const float* __restrict__ hw,
                 const float* __restrict__ hbias, float* __restrict__ rnn,
                 int* __restrict__ tags)
{
    __shared__ float wxlds[48 * 256];   // 48KB: x2h weights, this WG's 16 cols
    __shared__ float hlds[8 * 512];     // 16KB: h(t-1)
    __shared__ float xlds[8 * 256];     // 8KB:  x(t)
    __shared__ float pad_[2304];        // ballast -> ~81.5KB -> 1 WG/CU
    __shared__ int s_rk;

    const int tid = threadIdx.x;
    ((volatile float*)pad_)[tid & 2047] = 0.f;  // keep ballast allocated

    int xcc;
    asm volatile("s_getreg_b32 %0, hwreg(HW_REG_XCC_ID)" : "=s"(xcc));
    const int g = xcc & 7;               // group = physical XCD
    if (tid == 0) {
        __threadfence();                 // one-time: drop stale/poison lines
        s_rk = atomicAdd(tags + NWG * TAGPAD + g * 16, 1); // rank in XCD
    }
    __syncthreads();
    const int rk = s_rk;
    if (rk >= 32) return;                // cannot happen with 1 WG/CU

    const int w    = tid >> 6;           // wave 0..15
    const int l    = tid & 63;           // lane
    const int cp   = w >> 1;             // column pair 0..7
    const int bh   = w & 1;              // batch half 0..1
    const int c0w  = rk * 16 + 2 * cp;   // wave's first column
    const int s0 = l & 1, s1 = (l >> 1) & 1, s2 = (l >> 2) & 1;
    const int col  = c0w + s2;                 // epilogue column (lanes l<8)
    const int ob   = 8 * g + 4 * bh + (l & 3); // epilogue batch row (global)

    // h staging map: thread stages 4 contiguous floats
    const int sb    = tid >> 7;
    const int sk    = (tid & 127) * 4;
    const int soff  = sb * 512 + sk;
    const int hsoff = (8 * g + sb) * HH + sk;
    // x staging map: thread stages 2 contiguous floats
    const int sk2   = (tid & 127) * 2;
    const int soff2 = sb * 256 + sk2;
    const int xgoff = (8 * g + sb) * II + sk2;

    // poll: lanes tid<32 poll rank-tid's tag (LLC); tid0 releases ours
    const int* tpoll = tags + ((size_t)g * 32 + (tid & 31)) * TAGPAD;
    int* tagme       = (int*)(tags + ((size_t)g * 32 + rk) * TAGPAD);

    // lane-permuted rows for cndmask-free transpose-reduce
    const int r0 = 2*s1 + s0, r1 = r0 ^ 2, r2 = r0 ^ 1, r3 = r0 ^ 3;
    const int roff0 = (4*bh + r0) * 512 + 4*l;
    const int roff1 = (4*bh + r1) * 512 + 4*l;
    const int roff2 = (4*bh + r2) * 512 + 4*l;
    const int roff3 = (4*bh + r3) * 512 + 4*l;
    const int xoff0 = (4*bh + r0) * 256 + 4*l;
    const int xoff1 = (4*bh + r1) * 256 + 4*l;
    const int xoff2 = (4*bh + r2) * 256 + 4*l;
    const int xoff3 = (4*bh + r3) * 256 + 4*l;
    // wx LDS row offsets for slot parity 0/1 (col = c0w + (parity^s2))
    const int wxA = (2*cp + s2)       * 256 + 4*l;  // parity 0
    const int wxB = (2*cp + (1 - s2)) * 256 + 4*l;  // parity 1

    // fill wxlds: rows gate*16+lc  <-  xw[(gate*512 + rk*16 + lc)][:]
    for (int idx = tid; idx < 48 * 64; idx += 1024) {
        int row = idx >> 6, c4 = (idx & 63) * 4;
        int gate = row >> 4, lc = row & 15;
        float4 v = *(const float4*)(xw + ((size_t)gate * 512 + rk * 16 + lc) * II + c4);
        *(float4*)(wxlds + row * 256 + c4) = v;
    }
    // stage x[0]
    *(float2*)(xlds + soff2) = *(const float2*)(x + xgoff);

    // h2h weights -> registers: rr=2*gate+parity, col = c0w+(parity^s2)
    float wreg[6][8];
#pragma unroll
    for (int rr = 0; rr < 6; ++rr) {
        const float* wp = hw + ((size_t)(rr >> 1) * HH + c0w + ((rr & 1) ^ s2)) * HH;
        float4 a = *(const float4*)(wp + 4 * l);
        float4 b = *(const float4*)(wp + 256 + 4 * l);
        wreg[rr][0] = a.x; wreg[rr][1] = a.y; wreg[rr][2] = a.z; wreg[rr][3] = a.w;
        wreg[rr][4] = b.x; wreg[rr][5] = b.y; wreg[rr][6] = b.z; wreg[rr][7] = b.w;
    }
    // combined biases (r/u) + separate n-gate biases
    const float br_  = xb[col] + hbias[col];
    const float bu_  = xb[HH + col] + hbias[HH + col];
    const float bxn_ = xb[2 * HH + col];
    const float bhn_ = hbias[2 * HH + col];

    __syncthreads();   // wxlds + xlds ready

    float hloc = 0.f;            // lanes l<8: my (b,c) previous h (exact fp32)
    long long budget = 4000000;  // spin bound: bug -> wrong answer, not hang

    for (int t = 0; t < TT; ++t) {
        // prefetch x(t+1) (completes under poll/x-matvec)
        const int tn = (t + 1 < TT) ? t + 1 : TT - 1;
        const float2 xnv = *(const float2*)(x + ((size_t)tn << 14) + xgoff);

        // ---- x-projection for step t: matvec + reduce rounds 1..2 only ----
        // a2x[6] are the ONLY values that live across the barriers below.
        float a2x[6];
        {
            float4 xv0 = *(const float4*)(xlds + xoff0);
            float4 xv1 = *(const float4*)(xlds + xoff1);
            float4 xv2 = *(const float4*)(xlds + xoff2);
            float4 xv3 = *(const float4*)(xlds + xoff3);
            float xaA[6], xaB[6], xaC[6], xaD[6];
#pragma unroll
            for (int s = 0; s < 6; ++s) {
                const float* wp = wxlds + (s >> 1) * 4096 + ((s & 1) ? wxB : wxA);
                float4 wx = *(const float4*)wp;
                xaA[s] = fmaf(xv0.w, wx.w, fmaf(xv0.z, wx.z, fmaf(xv0.y, wx.y, xv0.x * wx.x)));
                xaB[s] = fmaf(xv1.w, wx.w, fmaf(xv1.z, wx.z, fmaf(xv1.y, wx.y, xv1.x * wx.x)));
                xaC[s] = fmaf(xv2.w, wx.w, fmaf(xv2.z, wx.z, fmaf(xv2.y, wx.y, xv2.x * wx.x)));
                xaD[s] = fmaf(xv3.w, wx.w, fmaf(xv3.z, wx.z, fmaf(xv3.y, wx.y, xv3.x * wx.x)));
            }
            float t0x[6], t1x[6];
#pragma unroll
            for (int s = 0; s < 6; ++s) {
                t0x[s] = xaA[s] + xor1_dpp(xaC[s]);
                t1x[s] = xaB[s] + xor1_dpp(xaD[s]);
            }
#pragma unroll
            for (int s = 0; s < 6; ++s)
                a2x[s] = t0x[s] + xor2_dpp(t1x[s]);
        }

        float a2h[6];
#pragma unroll
        for (int s = 0; s < 6; ++s) a2h[s] = 0.f;

        if (t > 0) {
            if (tid < 32) {  // poll the 32 group tags (LLC)
                int v;
                do {
                    asm volatile("global_load_dword %0, %1, off sc0 sc1\n\t"
                                 "s_waitcnt vmcnt(0)"
                                 : "=v"(v) : "v"(tpoll) : "memory");
                    if (v >= t) break;
                    __builtin_amdgcn_s_sleep(1);
                } while (--budget > 0);
            }
            __syncthreads(); // B1: h(t-1) complete in this XCD's L2

            // stage h(t-1) (16KB from L2)
            {
                const float* hs = rnn + ((size_t)(t - 1) << 15) + hsoff;
                *(float4*)(hlds + soff) = *(const float4*)hs;
            }
            __syncthreads(); // B2: h staged

            *(float2*)(xlds + soff2) = xnv; // restage x(t+1); reads were pre-B2

            // h-matvec (r7 shape: acc arrays live only in this region)
            float4 hA0 = *(const float4*)(hlds + roff0), hB0 = *(const float4*)(hlds + roff0 + 256);
            float4 hA1 = *(const float4*)(hlds + roff1), hB1 = *(const float4*)(hlds + roff1 + 256);
            float4 hA2 = *(const float4*)(hlds + roff2), hB2 = *(const float4*)(hlds + roff2 + 256);
            float4 hA3 = *(const float4*)(hlds + roff3), hB3 = *(const float4*)(hlds + roff3 + 256);
            float accA[6], accB[6], accC[6], accD[6];
#pragma unroll
            for (int rr = 0; rr < 6; ++rr) {
                float a;
                a = hA0.x * wreg[rr][0];
                a = fmaf(hA0.y, wreg[rr][1], a); a = fmaf(hA0.z, wreg[rr][2], a);
                a = fmaf(hA0.w, wreg[rr][3], a); a = fmaf(hB0.x, wreg[rr][4], a);
                a = fmaf(hB0.y, wreg[rr][5], a); a = fmaf(hB0.z, wreg[rr][6], a);
                a = fmaf(hB0.w, wreg[rr][7], a);
                accA[rr] = a;
                a = hA1.x * wreg[rr][0];
                a = fmaf(hA1.y, wreg[rr][1], a); a = fmaf(hA1.z, wreg[rr][2], a);
                a = fmaf(hA1.w, wreg[rr][3], a); a = fmaf(hB1.x, wreg[rr][4], a);
                a = fmaf(hB1.y, wreg[rr][5], a); a = fmaf(hB1.z, wreg[rr][6], a);
                a = fmaf(hB1.w, wreg[rr][7], a);
                accB[rr] = a;
                a = hA2.x * wreg[rr][0];
                a = fmaf(hA2.y, wreg[rr][1], a); a = fmaf(hA2.z, wreg[rr][2], a);
                a = fmaf(hA2.w, wreg[rr][3], a); a = fmaf(hB2.x, wreg[rr][4], a);
                a = fmaf(hB2.y, wreg[rr][5], a); a = fmaf(hB2.z, wreg[rr][6], a);
                a = fmaf(hB2.w, wreg[rr][7], a);
                accC[rr] = a;
                a = hA3.x * wreg[rr][0];
                a = fmaf(hA3.y, wreg[rr][1], a); a = fmaf(hA3.z, wreg[rr][2], a);
                a = fmaf(hA3.w, wreg[rr][3], a); a = fmaf(hB3.x, wreg[rr][4], a);
                a = fmaf(hB3.y, wreg[rr][5], a); a = fmaf(hB3.z, wreg[rr][6], a);
                a = fmaf(hB3.w, wreg[rr][7], a);
                accD[rr] = a;
            }
            float t0h[6], t1h[6];
#pragma unroll
            for (int rr = 0; rr < 6; ++rr) {
                t0h[rr] = accA[rr] + xor1_dpp(accC[rr]);
                t1h[rr] = accB[rr] + xor1_dpp(accD[rr]);
            }
#pragma unroll
            for (int rr = 0; rr < 6; ++rr)
                a2h[rr] = t0h[rr] + xor2_dpp(t1h[rr]);
        } else {
            __syncthreads();                // t=0: xlds reads done
            *(float2*)(xlds + soff2) = xnv; // restage x(1)
        }

        // ---- combined 8-slot tail: {r, u, x_n, h_n} x 2 col-parities ----
        float a3[4];
        {
            float cr0 = a2h[0] + a2x[0], cr1 = a2h[1] + a2x[1];
            float cu0 = a2h[2] + a2x[2], cu1 = a2h[3] + a2x[3];
            a3[0] = cr0    + __shfl_xor(cr1, 4, 64);
            a3[1] = cu0    + __shfl_xor(cu1, 4, 64);
            a3[2] = a2x[4] + __shfl_xor(a2x[5], 4, 64);
            a3[3] = a2h[4] + __shfl_xor(a2h[5], 4, 64);
        }
#pragma unroll
        for (int gi = 0; gi < 4; ++gi) {
            a3[gi] += __shfl_xor(a3[gi], 8, 64);
            a3[gi] += __shfl_xor(a3[gi], 16, 64);
            a3[gi] += __shfl_xor(a3[gi], 32, 64);
        }

        if (l < 8) { // one lane per output (b=ob, c=col)
            float rg = 1.f / (1.f + __expf(-(a3[0] + br_)));
            float ug = 1.f / (1.f + __expf(-(a3[1] + bu_)));
            // h2h bias of n-gate sits INSIDE reset*(...), per reference
            float npre = (a3[2] + bxn_) + rg * (a3[3] + bhn_);
            float e  = __expf(-2.f * npre);
            float nv = 2.f / (1.f + e) - 1.f;
            float hy = ug * hloc + (1.f - ug) * nv;
            hloc = hy;
            float* dstp = rnn + ((size_t)t << 15) + ob * HH + col;
            // plain store: write-through into this XCD's L2
            asm volatile("global_store_dword %0, %1, off"
                         :: "v"(dstp), "v"(hy) : "memory");
        }
        asm volatile("s_waitcnt vmcnt(0)" ::: "memory"); // h stores drained
        __syncthreads(); // B3: all waves' stores + xlds restage complete
        if (tid == 0) {
            int tv = t + 1;
            asm volatile("global_store_dword %0, %1, off sc0 sc1"
                         :: "v"(tagme), "v"(tv) : "memory");
        }
    }
}

// ---------------- Phase C: fc output (unchanged) ----------------
__global__ __launch_bounds__(256)
void fc_kernel(const float* __restrict__ rnn, const float* __restrict__ fcw,
               const float* __restrict__ fcb, float* __restrict__ out)
{
    __shared__ float wlds[128][65];
    const int t = blockIdx.x;
    const int tid = threadIdx.x;
    const int o  = tid & 63;
    const int bg = tid >> 6;
    float acc[16];
#pragma unroll
    for (int i = 0; i < 16; ++i) acc[i] = 0.f;

    for (int kc = 0; kc < 4; ++kc) {
        const int k0 = kc * 128;
        __syncthreads();
        for (int idx = tid; idx < 64 * 32; idx += 256) {
            int oo = idx >> 5, kq = (idx & 31) * 4;
            float4 v = *(const float4*)(fcw + (size_t)oo * HH + k0 + kq);
            wlds[kq][oo] = v.x; wlds[kq+1][oo] = v.y;
            wlds[kq+2][oo] = v.z; wlds[kq+3][oo] = v.w;
        }
        __syncthreads();
#pragma unroll 2
        for (int k4 = 0; k4 < 32; ++k4) {
            float w0 = wlds[k4*4+0][o], w1 = wlds[k4*4+1][o];
            float w2 = wlds[k4*4+2][o], w3 = wlds[k4*4+3][o];
#pragma unroll
            for (int i = 0; i < 16; ++i) {
                int bb = bg * 16 + i;
                float4 h4 = *(const float4*)(rnn + ((size_t)t * BB + bb) * HH + k0 + k4*4);
                acc[i] = fmaf(h4.x, w0, fmaf(h4.y, w1, fmaf(h4.z, w2, fmaf(h4.w, w3, acc[i]))));
            }
        }
    }
    float bo = fcb[o];
#pragma unroll
    for (int i = 0; i < 16; ++i) {
        int bb = bg * 16 + i;
        out[((size_t)t * BB + bb) * OO + o] = acc[i] + bo;
    }
}

extern "C" void kernel_launch(void* const* d_in, const int* in_sizes, int n_in,
                              void* d_out, int out_size, void* d_ws, size_t ws_size,
                              hipStream_t stream)
{
    const float* x     = (const float*)d_in[0];
    const float* x2h_w = (const float*)d_in[1];
    const float* x2h_b = (const float*)d_in[2];
    const float* h2h_w = (const float*)d_in[3];
    const float* h2h_b = (const float*)d_in[4];
    const float* fc_w  = (const float*)d_in[5];
    const float* fc_b  = (const float*)d_in[6];

    float* out = (float*)d_out;                        // [T][B][O]
    float* rnn = (float*)d_out + (size_t)TT * BB * OO; // [T][B][H]

    int* tags = (int*)d_ws;                            // 256 WG tags + rank ctrs

    hipMemsetAsync(tags, 0, (NWG * TAGPAD + 8 * 16) * sizeof(int), stream);

    scan_kernel<<<NWG, 1024, 0, stream>>>(x, x2h_w, x2h_b, h2h_w, h2h_b, rnn, tags);
    fc_kernel<<<TT, 256, 0, stream>>>(rnn, fc_w, fc_b, out);
}